// Round 6
// baseline (179.045 us; speedup 1.0000x reference)
//
#include <hip/hip_runtime.h>
#include <cstdint>

#define NB 2
#define LL 384
#define DIN 256
#define DE 128
#define NH 8
#define DH 32
#define HD 256          // NH*DH
#define SCALE 0.17677669529663687f

typedef __attribute__((ext_vector_type(8))) short bf16x8;
typedef __attribute__((ext_vector_type(4))) float f32x4;

static __device__ __forceinline__ unsigned short f2bf(float f) {
    uint32_t u = __builtin_bit_cast(uint32_t, f);
    u += 0x7FFF + ((u >> 16) & 1);          // RNE
    return (unsigned short)(u >> 16);
}
static __device__ __forceinline__ float bf2f(unsigned short u) {
    return __builtin_bit_cast(float, (uint32_t)u << 16);
}
static __device__ __forceinline__ float getf4(const float4& v, int k) {
    return k == 0 ? v.x : k == 1 ? v.y : k == 2 ? v.z : v.w;
}
static __device__ __forceinline__ bf16x8 pack8(const float4& a, const float4& b) {
    bf16x8 p;
    p[0]=(short)f2bf(a.x); p[1]=(short)f2bf(a.y); p[2]=(short)f2bf(a.z); p[3]=(short)f2bf(a.w);
    p[4]=(short)f2bf(b.x); p[5]=(short)f2bf(b.y); p[6]=(short)f2bf(b.z); p[7]=(short)f2bf(b.w);
    return p;
}

// ---------------- prep_we: We^T -> bf16 (HD x DE, n-major) ----------------
__global__ __launch_bounds__(128) void prep_we(const float* __restrict__ We,
                                               unsigned short* __restrict__ WeT) {
    const int n = blockIdx.x;    // 0..255
    const int k = threadIdx.x;   // 0..127
    WeT[n * DE + k] = f2bf(We[(size_t)k * HD + n]);
}

// ---------------- proj: q/k -> bf16, v/u -> fp32 ----------------
__global__ __launch_bounds__(256) void proj_kernel(
    const float* __restrict__ node,
    const float* __restrict__ Wq, const float* __restrict__ bq,
    const float* __restrict__ Wk, const float* __restrict__ bk,
    const float* __restrict__ Wv, const float* __restrict__ bv,
    const float* __restrict__ Wu, const float* __restrict__ bu,
    unsigned short* __restrict__ qb16, unsigned short* __restrict__ kb16,
    float* __restrict__ vb, float* __restrict__ ub)
{
    __shared__ __align__(16) float rows[4][DIN];
    const int t  = threadIdx.x;
    const int r0 = blockIdx.x * 4;

    #pragma unroll
    for (int r = 0; r < 4; ++r)
        rows[r][t] = node[(size_t)(r0 + r) * DIN + t];
    __syncthreads();

    float aq[4], ak[4], av[4], au[4];
    {
        const float vq = bq[t], vk = bk[t], vv = bv[t], vu = bu[t];
        #pragma unroll
        for (int r = 0; r < 4; ++r) { aq[r] = vq; ak[r] = vk; av[r] = vv; au[r] = vu; }
    }

    for (int f4 = 0; f4 < DIN / 4; ++f4) {
        float4 xv[4];
        #pragma unroll
        for (int r = 0; r < 4; ++r)
            xv[r] = *(const float4*)&rows[r][f4 * 4];
        #pragma unroll
        for (int k = 0; k < 4; ++k) {
            const int f = f4 * 4 + k;
            const float wq = Wq[(size_t)f * HD + t];
            const float wk = Wk[(size_t)f * HD + t];
            const float wv = Wv[(size_t)f * HD + t];
            const float wu = Wu[(size_t)f * HD + t];
            #pragma unroll
            for (int r = 0; r < 4; ++r) {
                const float x = getf4(xv[r], k);
                aq[r] += x * wq; ak[r] += x * wk; av[r] += x * wv; au[r] += x * wu;
            }
        }
    }

    #pragma unroll
    for (int r = 0; r < 4; ++r) {
        const size_t o = (size_t)(r0 + r) * HD + t;
        qb16[o] = f2bf(aq[r]); kb16[o] = f2bf(ak[r]);
        vb[o] = av[r]; ub[o] = au[r];
    }
}

// ---------------- vt: v (fp32, j-major) -> vT (bf16, col-major) ----------------
__global__ __launch_bounds__(256) void vt_kernel(const float* __restrict__ vb,
                                                 unsigned short* __restrict__ vT) {
    __shared__ float tile[64][65];
    int blk = blockIdx.x;
    const int b  = blk / 24; blk %= 24;
    const int jt = blk / 4;
    const int ct = blk % 4;
    const int j0 = jt * 64, c0 = ct * 64;
    const int t  = threadIdx.x;
    const int c  = t & 63, j4 = t >> 6;
    #pragma unroll
    for (int rr = 0; rr < 16; ++rr) {
        const int j = j4 + 4 * rr;
        tile[j][c] = vb[(size_t)(b * LL + j0 + j) * HD + c0 + c];
    }
    __syncthreads();
    const int jj = t & 63, c4 = t >> 6;
    #pragma unroll
    for (int rr = 0; rr < 16; ++rr) {
        const int cc = c4 + 4 * rr;
        vT[(size_t)(b * HD + c0 + cc) * LL + j0 + jj] = f2bf(tile[jj][cc]);
    }
}

// ---------------- qk: lpre[b,h,i,j] = SCALE*(q.k) - 1e9*(1-mask) ----------------
__global__ __launch_bounds__(256) void qk_kernel(
    const unsigned short* __restrict__ qb16, const unsigned short* __restrict__ kb16,
    const float* __restrict__ mask, float* __restrict__ logit_pre)
{
    int idx = blockIdx.x;
    const int jt = idx % 6; idx /= 6;
    const int it = idx % 6; idx /= 6;
    const int h  = idx % NH;
    const int b  = idx / NH;
    const int t    = threadIdx.x;
    const int lane = t & 63;
    const int w    = t >> 6;
    const int lid  = lane & 15;
    const int g    = lane >> 4;
    const int i0 = it * 64 + w * 16;
    const int j0 = jt * 64;

    const bf16x8 afr = *(const bf16x8*)&qb16[(size_t)(b * LL + i0 + lid) * HD + h * DH + g * 8];
    f32x4 acc[4];
    #pragma unroll
    for (int jj = 0; jj < 4; ++jj) {
        const bf16x8 bfrg = *(const bf16x8*)&kb16[(size_t)(b * LL + j0 + jj * 16 + lid) * HD + h * DH + g * 8];
        acc[jj] = __builtin_amdgcn_mfma_f32_16x16x32_bf16(afr, bfrg, (f32x4){0.f,0.f,0.f,0.f}, 0, 0, 0);
    }
    #pragma unroll
    for (int jj = 0; jj < 4; ++jj) {
        #pragma unroll
        for (int r = 0; r < 4; ++r) {
            const int i = i0 + 4 * g + r;
            const int j = j0 + jj * 16 + lid;
            const float lg = SCALE * acc[jj][r]
                           + (1.0f - mask[(size_t)(b * LL + i) * LL + j]) * -1e9f;
            logit_pre[((size_t)(b * NH + h) * LL + i) * LL + j] = lg;
        }
    }
}

// ---------------- qwe: qWe[b,i,h,c] = SCALE * sum_d q[b,i,h*32+d]*We[c,h*32+d] ----------------
__global__ __launch_bounds__(256) void qwe_kernel(
    const unsigned short* __restrict__ qb16, const unsigned short* __restrict__ WeT,
    unsigned short* __restrict__ qWe)
{
    const int bi = blockIdx.x;
    const int t  = threadIdx.x;
    const int h  = t >> 5;
    const int c0 = (t & 31) * 4;

    float qv[32];
    const unsigned short* qp = &qb16[(size_t)bi * HD + h * DH];
    #pragma unroll
    for (int d = 0; d < 32; ++d) qv[d] = bf2f(qp[d]);

    float acc0 = 0.f, acc1 = 0.f, acc2 = 0.f, acc3 = 0.f;
    #pragma unroll
    for (int d = 0; d < 32; ++d) {
        const ushort4 wt = *(const ushort4*)&WeT[(size_t)(h * DH + d) * DE + c0];
        acc0 += qv[d] * bf2f(wt.x); acc1 += qv[d] * bf2f(wt.y);
        acc2 += qv[d] * bf2f(wt.z); acc3 += qv[d] * bf2f(wt.w);
    }
    unsigned short* o = &qWe[(size_t)bi * (NH * DE) + h * DE + c0];
    o[0] = f2bf(SCALE * acc0); o[1] = f2bf(SCALE * acc1);
    o[2] = f2bf(SCALE * acc2); o[3] = f2bf(SCALE * acc3);
}

// ---------------- elog: lpre[b,h,i,j] += (E_i @ qWe_i^T)[j,h] ----------------
// grid = NB*LL*3 blocks, 256 threads = 4 waves. Wave w: j [32w,+32) of a 128-tile.
// All 16 edge float4 per lane HOISTED before any VALU/MFMA -> deep MLP.
// No LDS, no barriers.
__global__ __launch_bounds__(256, 2) void elog_kernel(
    const float* __restrict__ edge,            // (B,L,L,DE)
    const unsigned short* __restrict__ qWe,    // (B,L,NH,DE) bf16, SCALE folded
    float* __restrict__ lpre)                  // += edge-logits (in place)
{
    int idx = blockIdx.x;
    const int jt = idx % 3; idx /= 3;
    const int bi = idx;
    const int b = bi / LL, ii = bi % LL;
    const int t = threadIdx.x, lane = t & 63, w = t >> 6;
    const int lid = lane & 15, g = lane >> 4;
    const int hq = lid & 7;
    const int j0 = jt * 128 + w * 32;

    // hoisted edge loads: 16 independent float4, issued before any consumer
    float4 eL[2][4][2];
    #pragma unroll
    for (int mt = 0; mt < 2; ++mt) {
        const float* ef = edge + ((size_t)bi * LL + j0 + mt * 16 + lid) * DE;
        #pragma unroll
        for (int kt = 0; kt < 4; ++kt) {
            eL[mt][kt][0] = *(const float4*)&ef[kt * 32 + g * 8];
            eL[mt][kt][1] = *(const float4*)&ef[kt * 32 + g * 8 + 4];
        }
    }
    // hoisted qk logits (for +=) and qWe B-frags
    float* lrow = lpre + ((size_t)(b * NH + hq) * LL + ii) * LL;
    float4 qk4[2];
    #pragma unroll
    for (int mt = 0; mt < 2; ++mt)
        qk4[mt] = *(const float4*)&lrow[j0 + mt * 16 + 4 * g];

    bf16x8 qfr[4];
    {
        const unsigned short* qwp = &qWe[(size_t)bi * (NH * DE) + hq * DE];
        #pragma unroll
        for (int kt = 0; kt < 4; ++kt)
            qfr[kt] = *(const bf16x8*)&qwp[kt * 32 + g * 8];
    }

    // pack + MFMA: acc[mt] = E(32x128) @ qWe^T(128x16)
    f32x4 acc[2];
    #pragma unroll
    for (int mt = 0; mt < 2; ++mt) {
        acc[mt] = (f32x4){0.f, 0.f, 0.f, 0.f};
        #pragma unroll
        for (int kt = 0; kt < 4; ++kt) {
            const bf16x8 pk = pack8(eL[mt][kt][0], eL[mt][kt][1]);
            acc[mt] = __builtin_amdgcn_mfma_f32_16x16x32_bf16(pk, qfr[kt], acc[mt], 0, 0, 0);
        }
    }

    // lpre += e-logits (D row = 4g+r -> j, col = lid -> h; rows lid>=8 are dup heads)
    if (lid < 8) {
        #pragma unroll
        for (int mt = 0; mt < 2; ++mt) {
            float4 x = qk4[mt];
            x.x += acc[mt][0]; x.y += acc[mt][1];
            x.z += acc[mt][2]; x.w += acc[mt][3];
            *(float4*)&lrow[j0 + mt * 16 + 4 * g] = x;
        }
    }
}

// ---------------- smax: softmax(lpre[row,:]) -> attb (bf16) and attf (f32) ----------------
// grid = NB*NH*LL/4 blocks, 256 threads = 4 waves, one wave per row. No barriers.
__global__ __launch_bounds__(256) void smax_kernel(
    const float* __restrict__ lpre,
    unsigned short* __restrict__ attb, float* __restrict__ attf)
{
    const int t = threadIdx.x, lane = t & 63, w = t >> 6;
    const int row = blockIdx.x * 4 + w;            // 0..6143 = (b*NH+h)*LL+i
    const float* lr = lpre + (size_t)row * LL;

    float2 x[3];
    #pragma unroll
    for (int k = 0; k < 3; ++k)
        x[k] = *(const float2*)&lr[2 * lane + 128 * k];

    float m = fmaxf(x[0].x, x[0].y);
    m = fmaxf(m, fmaxf(x[1].x, x[1].y));
    m = fmaxf(m, fmaxf(x[2].x, x[2].y));
    #pragma unroll
    for (int off = 1; off < 64; off <<= 1) m = fmaxf(m, __shfl_xor(m, off));

    float p[6], s = 0.f;
    #pragma unroll
    for (int k = 0; k < 3; ++k) {
        p[2 * k]     = __expf(x[k].x - m);
        p[2 * k + 1] = __expf(x[k].y - m);
        s += p[2 * k] + p[2 * k + 1];
    }
    #pragma unroll
    for (int off = 1; off < 64; off <<= 1) s += __shfl_xor(s, off);
    const float inv = 1.0f / s;

    unsigned int* ao = (unsigned int*)attb + (size_t)row * (LL / 2);
    float* af = attf + (size_t)row * LL;
    #pragma unroll
    for (int k = 0; k < 3; ++k) {
        const float p0 = p[2 * k] * inv, p1 = p[2 * k + 1] * inv;
        const unsigned int pk = ((unsigned int)f2bf(p1) << 16) | (unsigned int)f2bf(p0);
        ao[lane + 64 * k] = pk;
        *(float2*)&af[2 * lane + 128 * k] = (float2){p0, p1};
    }
}

// ---------------- aek: aE[h,c] = sum_j attf[h,j] * edge[bi,j,c] (VALU, coalesced) ----
// grid = NB*LL blocks, 512 threads = 8 waves; wave w = head w; lane -> c-pair.
// Edge rows read as 512 B/instr coalesced float2; p broadcast from LDS (float4).
__global__ __launch_bounds__(512, 2) void aek_kernel(
    const float* __restrict__ edge,            // (B,L,L,DE)
    const float* __restrict__ attf,            // (B,NH,L,L) f32 softmaxed
    float* __restrict__ aEq)                   // (NB*LL, NH*DE)
{
    __shared__ float ps[NH][LL];   // 12 KiB
    const int bi = blockIdx.x, b = bi / LL, ii = bi % LL;
    const int t = threadIdx.x, lane = t & 63, w = t >> 6;

    // stage this block's 8 att rows (coalesced)
    {
        const float* ar = attf + ((size_t)(b * NH + w) * LL + ii) * LL;
        #pragma unroll
        for (int k = 0; k < 3; ++k)
            *(float2*)&ps[w][2 * lane + 128 * k] = *(const float2*)&ar[2 * lane + 128 * k];
    }
    __syncthreads();

    const float* eb = edge + (size_t)bi * LL * DE + 2 * lane;
    float2 acc = {0.f, 0.f};
    #pragma unroll 2
    for (int j = 0; j < LL; j += 4) {
        const float4 pv = *(const float4*)&ps[w][j];   // broadcast read
        const float2 e0 = *(const float2*)&eb[(size_t)(j + 0) * DE];
        const float2 e1 = *(const float2*)&eb[(size_t)(j + 1) * DE];
        const float2 e2 = *(const float2*)&eb[(size_t)(j + 2) * DE];
        const float2 e3 = *(const float2*)&eb[(size_t)(j + 3) * DE];
        acc.x += pv.x * e0.x; acc.y += pv.x * e0.y;
        acc.x += pv.y * e1.x; acc.y += pv.y * e1.y;
        acc.x += pv.z * e2.x; acc.y += pv.z * e2.y;
        acc.x += pv.w * e3.x; acc.y += pv.w * e3.y;
    }
    *(float2*)&aEq[(size_t)bi * (NH * DE) + w * DE + 2 * lane] = acc;
}

// ---------------- avk: av[hd] = sum_j p[h,j] * vT[hd,j] via MFMA (full K) ----------------
// grid = NB*LL blocks, 256 threads = 4 waves; wave w: hd [64w, 64w+64). All vector loads.
__global__ __launch_bounds__(256, 2) void avk_kernel(
    const unsigned short* __restrict__ attb,   // (B,NH,L,L) bf16 softmaxed
    const unsigned short* __restrict__ vT,     // (B,HD,L) bf16
    float* __restrict__ avq)                   // (NB*LL, HD)
{
    const int bi = blockIdx.x, b = bi / LL, ii = bi % LL;
    const int t = threadIdx.x, lane = t & 63, w = t >> 6;
    const int lid = lane & 15, g = lane >> 4;
    const int h8 = lid & 7;

    // p A-frags: A[m=h][k=j] (rows 8..15 dup, outputs discarded)
    bf16x8 pA[12];
    {
        const unsigned short* ab = attb + ((size_t)(b * NH + h8) * LL + ii) * LL;
        #pragma unroll
        for (int kt = 0; kt < 12; ++kt)
            pA[kt] = *(const bf16x8*)&ab[kt * 32 + g * 8];
    }

    const unsigned short* vTb = vT + (size_t)b * HD * LL;
    #pragma unroll
    for (int nt = 0; nt < 4; ++nt) {
        const int hd = 64 * w + nt * 16 + lid;
        const unsigned short* vr = &vTb[(size_t)hd * LL];
        f32x4 acc = (f32x4){0.f, 0.f, 0.f, 0.f};
        #pragma unroll
        for (int kt = 0; kt < 12; ++kt) {
            const bf16x8 vv = *(const bf16x8*)&vr[kt * 32 + g * 8];
            acc = __builtin_amdgcn_mfma_f32_16x16x32_bf16(pA[kt], vv, acc, 0, 0, 0);
        }
        const int h = 2 * w + (nt >> 1);       // head of this hd-chunk
        if (g == (h >> 2)) {
            const int r = h & 3;
            const float val = r == 0 ? acc[0] : r == 1 ? acc[1] : r == 2 ? acc[2] : acc[3];
            avq[(size_t)bi * HD + hd] = val;
        }
    }
}

// ---------------- finale: out = u + av + aE @ We_h ----------------
__global__ __launch_bounds__(256) void finale_kernel(
    const float* __restrict__ aEq, const float* __restrict__ avq,
    const float* __restrict__ We,              // (DE, HD) fp32
    const float* __restrict__ ub,
    float* __restrict__ out)
{
    __shared__ float aEs[NH * DE];  // 4 KiB
    const int bi = blockIdx.x, t = threadIdx.x;

    #pragma unroll
    for (int q = 0; q < 4; ++q)
        aEs[t + 256 * q] = aEq[(size_t)bi * (NH * DE) + t + 256 * q];
    __syncthreads();

    const int hd = t, h = hd >> 5;
    float acc = ub[(size_t)bi * HD + hd] + avq[(size_t)bi * HD + hd];

    const float* sa = &aEs[h * DE];
    float a0 = 0.f, a1 = 0.f, a2 = 0.f, a3 = 0.f;
    #pragma unroll
    for (int c = 0; c < DE; c += 4) {
        a0 += sa[c]     * We[(size_t)(c)     * HD + hd];
        a1 += sa[c + 1] * We[(size_t)(c + 1) * HD + hd];
        a2 += sa[c + 2] * We[(size_t)(c + 2) * HD + hd];
        a3 += sa[c + 3] * We[(size_t)(c + 3) * HD + hd];
    }
    out[(size_t)bi * HD + hd] = acc + ((a0 + a1) + (a2 + a3));
}

extern "C" void kernel_launch(void* const* d_in, const int* in_sizes, int n_in,
                              void* d_out, int out_size, void* d_ws, size_t ws_size,
                              hipStream_t stream) {
    const float* node = (const float*)d_in[0];
    const float* edge = (const float*)d_in[1];
    const float* mask = (const float*)d_in[2];
    const float* Wq   = (const float*)d_in[3];
    const float* bq   = (const float*)d_in[4];
    const float* Wk   = (const float*)d_in[5];
    const float* bk   = (const float*)d_in[6];
    const float* Wv   = (const float*)d_in[7];
    const float* bv   = (const float*)d_in[8];
    const float* We   = (const float*)d_in[9];
    const float* Wu   = (const float*)d_in[10];
    const float* bu   = (const float*)d_in[11];
    float* out = (float*)d_out;

    const size_t rowsz = (size_t)NB * LL * HD;            // 196608
    const size_t lsz   = (size_t)NB * NH * LL * LL;       // 2359296
    float* ws   = (float*)d_ws;
    float* vb   = ws;
    float* ubuf = vb + rowsz;
    float* lpre = ubuf + rowsz;                           // lsz
    float* attf = lpre + lsz;                             // lsz
    float* aEq  = attf + lsz;                             // NB*LL*NH*DE = 786432
    float* avq  = aEq + (size_t)NB * LL * NH * DE;        // NB*LL*HD = 196608
    unsigned short* us   = (unsigned short*)(avq + rowsz);
    unsigned short* WeT  = us;                            // HD*DE = 32768
    unsigned short* qb16 = WeT + (size_t)HD * DE;
    unsigned short* kb16 = qb16 + rowsz;
    unsigned short* vT   = kb16 + rowsz;
    unsigned short* qWeB = vT + rowsz;                    // NB*LL*NH*DE
    unsigned short* attb = qWeB + (size_t)NB * LL * NH * DE; // lsz u16

    hipLaunchKernelGGL(prep_we, dim3(HD), dim3(DE), 0, stream, We, WeT);
    hipLaunchKernelGGL(proj_kernel, dim3(NB * LL / 4), dim3(256), 0, stream,
                       node, Wq, bq, Wk, bk, Wv, bv, Wu, bu, qb16, kb16, vb, ubuf);
    hipLaunchKernelGGL(vt_kernel, dim3(NB * (LL / 64) * (HD / 64)), dim3(256), 0, stream,
                       vb, vT);
    hipLaunchKernelGGL(qk_kernel, dim3(NB * NH * (LL / 64) * (LL / 64)), dim3(256), 0, stream,
                       qb16, kb16, mask, lpre);
    hipLaunchKernelGGL(qwe_kernel, dim3(NB * LL), dim3(256), 0, stream,
                       qb16, WeT, qWeB);
    hipLaunchKernelGGL(elog_kernel, dim3(NB * LL * 3), dim3(256), 0, stream,
                       edge, qWeB, lpre);
    hipLaunchKernelGGL(smax_kernel, dim3(NB * NH * LL / 4), dim3(256), 0, stream,
                       lpre, attb, attf);
    hipLaunchKernelGGL(aek_kernel, dim3(NB * LL), dim3(512), 0, stream,
                       edge, attf, aEq);
    hipLaunchKernelGGL(avk_kernel, dim3(NB * LL), dim3(256), 0, stream,
                       attb, vT, avq);
    hipLaunchKernelGGL(finale_kernel, dim3(NB * LL), dim3(256), 0, stream,
                       aEq, avq, We, ubuf, out);
}

// Round 7
// 131.158 us; speedup vs baseline: 1.3651x; 1.3651x over previous
//
#include <hip/hip_runtime.h>
#include <cstdint>

#define NB 2
#define LL 384
#define DIN 256
#define DE 128
#define NH 8
#define DH 32
#define HD 256          // NH*DH
#define SCALE 0.17677669529663687f
#define PSPAD 12        // ps row stride (floats): 16B-aligned float4s, ~2-way banks

typedef __attribute__((ext_vector_type(8))) short bf16x8;
typedef __attribute__((ext_vector_type(4))) float f32x4;

static __device__ __forceinline__ unsigned short f2bf(float f) {
    uint32_t u = __builtin_bit_cast(uint32_t, f);
    u += 0x7FFF + ((u >> 16) & 1);          // RNE
    return (unsigned short)(u >> 16);
}
static __device__ __forceinline__ float bf2f(unsigned short u) {
    return __builtin_bit_cast(float, (uint32_t)u << 16);
}
static __device__ __forceinline__ float getf4(const float4& v, int k) {
    return k == 0 ? v.x : k == 1 ? v.y : k == 2 ? v.z : v.w;
}
static __device__ __forceinline__ bf16x8 pack8(const float4& a, const float4& b) {
    bf16x8 p;
    p[0]=(short)f2bf(a.x); p[1]=(short)f2bf(a.y); p[2]=(short)f2bf(a.z); p[3]=(short)f2bf(a.w);
    p[4]=(short)f2bf(b.x); p[5]=(short)f2bf(b.y); p[6]=(short)f2bf(b.z); p[7]=(short)f2bf(b.w);
    return p;
}

// ---------------- prep_we: We^T -> bf16 (HD x DE, n-major) ----------------
__global__ __launch_bounds__(128) void prep_we(const float* __restrict__ We,
                                               unsigned short* __restrict__ WeT) {
    const int n = blockIdx.x;    // 0..255
    const int k = threadIdx.x;   // 0..127
    WeT[n * DE + k] = f2bf(We[(size_t)k * HD + n]);
}

// ---------------- proj: q/k -> bf16, v/u -> fp32 ----------------
__global__ __launch_bounds__(256) void proj_kernel(
    const float* __restrict__ node,
    const float* __restrict__ Wq, const float* __restrict__ bq,
    const float* __restrict__ Wk, const float* __restrict__ bk,
    const float* __restrict__ Wv, const float* __restrict__ bv,
    const float* __restrict__ Wu, const float* __restrict__ bu,
    unsigned short* __restrict__ qb16, unsigned short* __restrict__ kb16,
    float* __restrict__ vb, float* __restrict__ ub)
{
    __shared__ __align__(16) float rows[4][DIN];
    const int t  = threadIdx.x;
    const int r0 = blockIdx.x * 4;

    #pragma unroll
    for (int r = 0; r < 4; ++r)
        rows[r][t] = node[(size_t)(r0 + r) * DIN + t];
    __syncthreads();

    float aq[4], ak[4], av[4], au[4];
    {
        const float vq = bq[t], vk = bk[t], vv = bv[t], vu = bu[t];
        #pragma unroll
        for (int r = 0; r < 4; ++r) { aq[r] = vq; ak[r] = vk; av[r] = vv; au[r] = vu; }
    }

    for (int f4 = 0; f4 < DIN / 4; ++f4) {
        float4 xv[4];
        #pragma unroll
        for (int r = 0; r < 4; ++r)
            xv[r] = *(const float4*)&rows[r][f4 * 4];
        #pragma unroll
        for (int k = 0; k < 4; ++k) {
            const int f = f4 * 4 + k;
            const float wq = Wq[(size_t)f * HD + t];
            const float wk = Wk[(size_t)f * HD + t];
            const float wv = Wv[(size_t)f * HD + t];
            const float wu = Wu[(size_t)f * HD + t];
            #pragma unroll
            for (int r = 0; r < 4; ++r) {
                const float x = getf4(xv[r], k);
                aq[r] += x * wq; ak[r] += x * wk; av[r] += x * wv; au[r] += x * wu;
            }
        }
    }

    #pragma unroll
    for (int r = 0; r < 4; ++r) {
        const size_t o = (size_t)(r0 + r) * HD + t;
        qb16[o] = f2bf(aq[r]); kb16[o] = f2bf(ak[r]);
        vb[o] = av[r]; ub[o] = au[r];
    }
}

// ---------------- vt: v (fp32, j-major) -> vT (bf16, col-major) ----------------
__global__ __launch_bounds__(256) void vt_kernel(const float* __restrict__ vb,
                                                 unsigned short* __restrict__ vT) {
    __shared__ float tile[64][65];
    int blk = blockIdx.x;
    const int b  = blk / 24; blk %= 24;
    const int jt = blk / 4;
    const int ct = blk % 4;
    const int j0 = jt * 64, c0 = ct * 64;
    const int t  = threadIdx.x;
    const int c  = t & 63, j4 = t >> 6;
    #pragma unroll
    for (int rr = 0; rr < 16; ++rr) {
        const int j = j4 + 4 * rr;
        tile[j][c] = vb[(size_t)(b * LL + j0 + j) * HD + c0 + c];
    }
    __syncthreads();
    const int jj = t & 63, c4 = t >> 6;
    #pragma unroll
    for (int rr = 0; rr < 16; ++rr) {
        const int cc = c4 + 4 * rr;
        vT[(size_t)(b * HD + c0 + cc) * LL + j0 + jj] = f2bf(tile[jj][cc]);
    }
}

// ---------------- qk: lpre[b,h,i,j] = SCALE*(q.k) - 1e9*(1-mask) ----------------
__global__ __launch_bounds__(256) void qk_kernel(
    const unsigned short* __restrict__ qb16, const unsigned short* __restrict__ kb16,
    const float* __restrict__ mask, float* __restrict__ logit_pre)
{
    int idx = blockIdx.x;
    const int jt = idx % 6; idx /= 6;
    const int it = idx % 6; idx /= 6;
    const int h  = idx % NH;
    const int b  = idx / NH;
    const int t    = threadIdx.x;
    const int lane = t & 63;
    const int w    = t >> 6;
    const int lid  = lane & 15;
    const int g    = lane >> 4;
    const int i0 = it * 64 + w * 16;
    const int j0 = jt * 64;

    const bf16x8 afr = *(const bf16x8*)&qb16[(size_t)(b * LL + i0 + lid) * HD + h * DH + g * 8];
    f32x4 acc[4];
    #pragma unroll
    for (int jj = 0; jj < 4; ++jj) {
        const bf16x8 bfrg = *(const bf16x8*)&kb16[(size_t)(b * LL + j0 + jj * 16 + lid) * HD + h * DH + g * 8];
        acc[jj] = __builtin_amdgcn_mfma_f32_16x16x32_bf16(afr, bfrg, (f32x4){0.f,0.f,0.f,0.f}, 0, 0, 0);
    }
    #pragma unroll
    for (int jj = 0; jj < 4; ++jj) {
        #pragma unroll
        for (int r = 0; r < 4; ++r) {
            const int i = i0 + 4 * g + r;
            const int j = j0 + jj * 16 + lid;
            const float lg = SCALE * acc[jj][r]
                           + (1.0f - mask[(size_t)(b * LL + i) * LL + j]) * -1e9f;
            logit_pre[((size_t)(b * NH + h) * LL + i) * LL + j] = lg;
        }
    }
}

// ---------------- qwe: qWe[b,i,h,c] = SCALE * sum_d q[b,i,h*32+d]*We[c,h*32+d] ----------------
__global__ __launch_bounds__(256) void qwe_kernel(
    const unsigned short* __restrict__ qb16, const unsigned short* __restrict__ WeT,
    unsigned short* __restrict__ qWe)
{
    const int bi = blockIdx.x;
    const int t  = threadIdx.x;
    const int h  = t >> 5;
    const int c0 = (t & 31) * 4;

    float qv[32];
    const unsigned short* qp = &qb16[(size_t)bi * HD + h * DH];
    #pragma unroll
    for (int d = 0; d < 32; ++d) qv[d] = bf2f(qp[d]);

    float acc0 = 0.f, acc1 = 0.f, acc2 = 0.f, acc3 = 0.f;
    #pragma unroll
    for (int d = 0; d < 32; ++d) {
        const ushort4 wt = *(const ushort4*)&WeT[(size_t)(h * DH + d) * DE + c0];
        acc0 += qv[d] * bf2f(wt.x); acc1 += qv[d] * bf2f(wt.y);
        acc2 += qv[d] * bf2f(wt.z); acc3 += qv[d] * bf2f(wt.w);
    }
    unsigned short* o = &qWe[(size_t)bi * (NH * DE) + h * DE + c0];
    o[0] = f2bf(SCALE * acc0); o[1] = f2bf(SCALE * acc1);
    o[2] = f2bf(SCALE * acc2); o[3] = f2bf(SCALE * acc3);
}

// ---------------- elog: lpre[b,h,i,j] += (E_i @ qWe_i^T)[j,h] ----------------
// grid = NB*LL*3 blocks, 256 threads = 4 waves. Wave w: j [32w,+32) of a 128-tile.
// All 16 edge float4 per lane HOISTED before any VALU/MFMA. No LDS, no barriers.
__global__ __launch_bounds__(256, 2) void elog_kernel(
    const float* __restrict__ edge,            // (B,L,L,DE)
    const unsigned short* __restrict__ qWe,    // (B,L,NH,DE) bf16, SCALE folded
    float* __restrict__ lpre)                  // += edge-logits (in place)
{
    int idx = blockIdx.x;
    const int jt = idx % 3; idx /= 3;
    const int bi = idx;
    const int b = bi / LL, ii = bi % LL;
    const int t = threadIdx.x, lane = t & 63, w = t >> 6;
    const int lid = lane & 15, g = lane >> 4;
    const int hq = lid & 7;
    const int j0 = jt * 128 + w * 32;

    // hoisted edge loads: 16 independent float4, issued before any consumer
    float4 eL[2][4][2];
    #pragma unroll
    for (int mt = 0; mt < 2; ++mt) {
        const float* ef = edge + ((size_t)bi * LL + j0 + mt * 16 + lid) * DE;
        #pragma unroll
        for (int kt = 0; kt < 4; ++kt) {
            eL[mt][kt][0] = *(const float4*)&ef[kt * 32 + g * 8];
            eL[mt][kt][1] = *(const float4*)&ef[kt * 32 + g * 8 + 4];
        }
    }
    // hoisted qk logits (for +=) and qWe B-frags
    float* lrow = lpre + ((size_t)(b * NH + hq) * LL + ii) * LL;
    float4 qk4[2];
    #pragma unroll
    for (int mt = 0; mt < 2; ++mt)
        qk4[mt] = *(const float4*)&lrow[j0 + mt * 16 + 4 * g];

    bf16x8 qfr[4];
    {
        const unsigned short* qwp = &qWe[(size_t)bi * (NH * DE) + hq * DE];
        #pragma unroll
        for (int kt = 0; kt < 4; ++kt)
            qfr[kt] = *(const bf16x8*)&qwp[kt * 32 + g * 8];
    }

    // pack + MFMA: acc[mt] = E(32x128) @ qWe^T(128x16)
    f32x4 acc[2];
    #pragma unroll
    for (int mt = 0; mt < 2; ++mt) {
        acc[mt] = (f32x4){0.f, 0.f, 0.f, 0.f};
        #pragma unroll
        for (int kt = 0; kt < 4; ++kt) {
            const bf16x8 pk = pack8(eL[mt][kt][0], eL[mt][kt][1]);
            acc[mt] = __builtin_amdgcn_mfma_f32_16x16x32_bf16(pk, qfr[kt], acc[mt], 0, 0, 0);
        }
    }

    // lpre += e-logits (D row = 4g+r -> j, col = lid -> h; rows lid>=8 are dup heads)
    if (lid < 8) {
        #pragma unroll
        for (int mt = 0; mt < 2; ++mt) {
            float4 x = qk4[mt];
            x.x += acc[mt][0]; x.y += acc[mt][1];
            x.z += acc[mt][2]; x.w += acc[mt][3];
            *(float4*)&lrow[j0 + mt * 16 + 4 * g] = x;
        }
    }
}

// ---------------- smax: attb[row,:] = softmax(lpre[row,:]) as bf16 ----------------
// grid = NB*NH*LL/4 blocks, 256 threads = 4 waves, one wave per row. No barriers.
__global__ __launch_bounds__(256) void smax_kernel(
    const float* __restrict__ lpre, unsigned short* __restrict__ attb)
{
    const int t = threadIdx.x, lane = t & 63, w = t >> 6;
    const int row = blockIdx.x * 4 + w;            // 0..6143 = (b*NH+h)*LL+i
    const float* lr = lpre + (size_t)row * LL;

    float2 x[3];
    #pragma unroll
    for (int k = 0; k < 3; ++k)
        x[k] = *(const float2*)&lr[2 * lane + 128 * k];

    float m = fmaxf(x[0].x, x[0].y);
    m = fmaxf(m, fmaxf(x[1].x, x[1].y));
    m = fmaxf(m, fmaxf(x[2].x, x[2].y));
    #pragma unroll
    for (int off = 1; off < 64; off <<= 1) m = fmaxf(m, __shfl_xor(m, off));

    float p[6], s = 0.f;
    #pragma unroll
    for (int k = 0; k < 3; ++k) {
        p[2 * k]     = __expf(x[k].x - m);
        p[2 * k + 1] = __expf(x[k].y - m);
        s += p[2 * k] + p[2 * k + 1];
    }
    #pragma unroll
    for (int off = 1; off < 64; off <<= 1) s += __shfl_xor(s, off);
    const float inv = 1.0f / s;

    unsigned int* ao = (unsigned int*)attb + (size_t)row * (LL / 2);
    #pragma unroll
    for (int k = 0; k < 3; ++k) {
        const unsigned int pk = ((unsigned int)f2bf(p[2 * k + 1] * inv) << 16)
                              |  (unsigned int)f2bf(p[2 * k] * inv);
        ao[lane + 64 * k] = pk;
    }
}

// ---------------- avk: av[hd] = sum_j p[h,j] * vT[hd,j] via MFMA (full K) ----------------
// grid = NB*LL blocks, 256 threads = 4 waves; wave w: hd [64w, 64w+64). All vector loads.
__global__ __launch_bounds__(256, 2) void avk_kernel(
    const unsigned short* __restrict__ attb,   // (B,NH,L,L) bf16 softmaxed
    const unsigned short* __restrict__ vT,     // (B,HD,L) bf16
    float* __restrict__ avq)                   // (NB*LL, HD)
{
    const int bi = blockIdx.x, b = bi / LL, ii = bi % LL;
    const int t = threadIdx.x, lane = t & 63, w = t >> 6;
    const int lid = lane & 15, g = lane >> 4;
    const int h8 = lid & 7;

    // p A-frags: A[m=h][k=j] (rows 8..15 dup, outputs discarded)
    bf16x8 pA[12];
    {
        const unsigned short* ab = attb + ((size_t)(b * NH + h8) * LL + ii) * LL;
        #pragma unroll
        for (int kt = 0; kt < 12; ++kt)
            pA[kt] = *(const bf16x8*)&ab[kt * 32 + g * 8];
    }

    const unsigned short* vTb = vT + (size_t)b * HD * LL;
    #pragma unroll
    for (int nt = 0; nt < 4; ++nt) {
        const int hd = 64 * w + nt * 16 + lid;
        const unsigned short* vr = &vTb[(size_t)hd * LL];
        f32x4 acc = (f32x4){0.f, 0.f, 0.f, 0.f};
        #pragma unroll
        for (int kt = 0; kt < 12; ++kt) {
            const bf16x8 vv = *(const bf16x8*)&vr[kt * 32 + g * 8];
            acc = __builtin_amdgcn_mfma_f32_16x16x32_bf16(pA[kt], vv, acc, 0, 0, 0);
        }
        const int h = 2 * w + (nt >> 1);       // head of this hd-chunk
        if (g == (h >> 2)) {
            const int r = h & 3;
            const float val = r == 0 ? acc[0] : r == 1 ? acc[1] : r == 2 ? acc[2] : acc[3];
            avq[(size_t)bi * HD + hd] = val;
        }
    }
}

// ---------------- aek2: aE[h,c] = sum_j p[h,j]*E[j,c] (VALU) + fused finale ----------------
// grid = NB*LL blocks, 512 threads = 8 waves. Wave w owns j-slice [48w,48w+48) for
// ALL 8 heads: edge block read exactly ONCE per block, 1 KB/instr coalesced
// (lane: r=lane>>5 row-pair half, c0=(lane&31)*4). p staged transposed [j][h] f32 in
// LDS (pad 12 -> aligned float4 broadcast reads). shfl r-reduce + LDS wave-tree,
// then fused epilogue out = u + av + aE@We.
__global__ __launch_bounds__(512, 2) void aek2_kernel(
    const float* __restrict__ edge,            // (B,L,L,DE)
    const unsigned short* __restrict__ attb,   // (B,NH,L,L) bf16 softmaxed
    const float* __restrict__ avq,             // (NB*LL, HD)
    const float* __restrict__ We,              // (DE, HD) fp32
    const float* __restrict__ ub,
    float* __restrict__ out)
{
    __shared__ __align__(16) float ps[LL][PSPAD];     // 18 KiB: p transposed [j][h]
    __shared__ __align__(16) float aEp[NH][NH][DE];   // 32 KiB: [wave][h][c] partials

    const int bi = blockIdx.x, b = bi / LL, ii = bi % LL;
    const int t = threadIdx.x, lane = t & 63, w = t >> 6;

    // stage p: wave w unpacks head w's att row (coalesced u32 reads)
    {
        const unsigned int* ar = (const unsigned int*)attb
                               + ((size_t)(b * NH + w) * LL + ii) * (LL / 2);
        #pragma unroll
        for (int k = 0; k < 3; ++k) {
            const unsigned int u = ar[lane + 64 * k];
            const int j2 = 2 * (lane + 64 * k);
            ps[j2][w]     = bf2f((unsigned short)(u & 0xffff));
            ps[j2 + 1][w] = bf2f((unsigned short)(u >> 16));
        }
    }
    __syncthreads();

    // main: wave w covers j in [48w, 48w+48)
    const int r  = lane >> 5;            // row within pair
    const int c0 = (lane & 31) * 4;      // c-quad
    float4 acc[NH];
    #pragma unroll
    for (int h = 0; h < NH; ++h) acc[h] = (float4){0.f, 0.f, 0.f, 0.f};

    const float* eb = edge + (size_t)bi * LL * DE;
    #pragma unroll 4
    for (int k = 0; k < 24; ++k) {
        const int j = w * 48 + 2 * k + r;
        const float4 ev = *(const float4*)&eb[(size_t)j * DE + c0];
        const float4 p0 = *(const float4*)&ps[j][0];
        const float4 p1 = *(const float4*)&ps[j][4];
        const float pj[8] = {p0.x, p0.y, p0.z, p0.w, p1.x, p1.y, p1.z, p1.w};
        #pragma unroll
        for (int h = 0; h < 8; ++h) {
            acc[h].x += pj[h] * ev.x; acc[h].y += pj[h] * ev.y;
            acc[h].z += pj[h] * ev.z; acc[h].w += pj[h] * ev.w;
        }
    }

    // reduce the two row-halves (lane ^ 32 shares c0)
    #pragma unroll
    for (int h = 0; h < 8; ++h) {
        acc[h].x += __shfl_xor(acc[h].x, 32);
        acc[h].y += __shfl_xor(acc[h].y, 32);
        acc[h].z += __shfl_xor(acc[h].z, 32);
        acc[h].w += __shfl_xor(acc[h].w, 32);
    }
    if (lane < 32) {
        #pragma unroll
        for (int h = 0; h < 8; ++h)
            *(float4*)&aEp[w][h][c0] = acc[h];
    }
    __syncthreads();

    // cross-wave tree: thread t owns 2 (h,c) entries; result into aEp[0]
    {
        const int flat = t * 2, h = flat >> 7, c = flat & 127;
        float sx = 0.f, sy = 0.f;
        #pragma unroll
        for (int w2 = 0; w2 < 8; ++w2) {
            sx += aEp[w2][h][c];
            sy += aEp[w2][h][c + 1];
        }
        aEp[0][h][c] = sx; aEp[0][h][c + 1] = sy;   // sole reader/writer per entry
    }
    __syncthreads();

    // fused epilogue: out = u + av + aE @ We_h
    if (t < HD) {
        const int hd = t, h = hd >> 5;
        float o = ub[(size_t)bi * HD + hd] + avq[(size_t)bi * HD + hd];
        const float* sa = &aEp[0][h][0];
        float a0 = 0.f, a1 = 0.f, a2 = 0.f, a3 = 0.f;
        #pragma unroll
        for (int c = 0; c < DE; c += 4) {
            a0 += sa[c]     * We[(size_t)(c)     * HD + hd];
            a1 += sa[c + 1] * We[(size_t)(c + 1) * HD + hd];
            a2 += sa[c + 2] * We[(size_t)(c + 2) * HD + hd];
            a3 += sa[c + 3] * We[(size_t)(c + 3) * HD + hd];
        }
        out[(size_t)bi * HD + hd] = o + ((a0 + a1) + (a2 + a3));
    }
}

extern "C" void kernel_launch(void* const* d_in, const int* in_sizes, int n_in,
                              void* d_out, int out_size, void* d_ws, size_t ws_size,
                              hipStream_t stream) {
    const float* node = (const float*)d_in[0];
    const float* edge = (const float*)d_in[1];
    const float* mask = (const float*)d_in[2];
    const float* Wq   = (const float*)d_in[3];
    const float* bq   = (const float*)d_in[4];
    const float* Wk   = (const float*)d_in[5];
    const float* bk   = (const float*)d_in[6];
    const float* Wv   = (const float*)d_in[7];
    const float* bv   = (const float*)d_in[8];
    const float* We   = (const float*)d_in[9];
    const float* Wu   = (const float*)d_in[10];
    const float* bu   = (const float*)d_in[11];
    float* out = (float*)d_out;

    const size_t rowsz = (size_t)NB * LL * HD;            // 196608
    const size_t lsz   = (size_t)NB * NH * LL * LL;       // 2359296
    float* ws   = (float*)d_ws;
    float* vb   = ws;
    float* ubuf = vb + rowsz;
    float* lpre = ubuf + rowsz;                           // lsz
    float* avq  = lpre + lsz;                             // rowsz
    unsigned short* us   = (unsigned short*)(avq + rowsz);
    unsigned short* WeT  = us;                            // HD*DE = 32768
    unsigned short* qb16 = WeT + (size_t)HD * DE;
    unsigned short* kb16 = qb16 + rowsz;
    unsigned short* vT   = kb16 + rowsz;
    unsigned short* qWeB = vT + rowsz;                    // NB*LL*NH*DE
    unsigned short* attb = qWeB + (size_t)NB * LL * NH * DE; // lsz u16

    hipLaunchKernelGGL(prep_we, dim3(HD), dim3(DE), 0, stream, We, WeT);
    hipLaunchKernelGGL(proj_kernel, dim3(NB * LL / 4), dim3(256), 0, stream,
                       node, Wq, bq, Wk, bk, Wv, bv, Wu, bu, qb16, kb16, vb, ubuf);
    hipLaunchKernelGGL(vt_kernel, dim3(NB * (LL / 64) * (HD / 64)), dim3(256), 0, stream,
                       vb, vT);
    hipLaunchKernelGGL(qk_kernel, dim3(NB * NH * (LL / 64) * (LL / 64)), dim3(256), 0, stream,
                       qb16, kb16, mask, lpre);
    hipLaunchKernelGGL(qwe_kernel, dim3(NB * LL), dim3(256), 0, stream,
                       qb16, WeT, qWeB);
    hipLaunchKernelGGL(elog_kernel, dim3(NB * LL * 3), dim3(256), 0, stream,
                       edge, qWeB, lpre);
    hipLaunchKernelGGL(smax_kernel, dim3(NB * NH * LL / 4), dim3(256), 0, stream,
                       lpre, attb);
    hipLaunchKernelGGL(avk_kernel, dim3(NB * LL), dim3(256), 0, stream,
                       attb, vT, avq);
    hipLaunchKernelGGL(aek2_kernel, dim3(NB * LL), dim3(512), 0, stream,
                       edge, attb, avq, We, ubuf, out);
}